// Round 1
// baseline (833.580 us; speedup 1.0000x reference)
//
#include <hip/hip_runtime.h>
#include <hip/hip_bf16.h>
#include <cstdint>

// Problem constants
#define B_  128
#define F_  512
#define T_  60
#define C_  15
#define H1_ 128
#define H2_ 64

// ---------------------------------------------------------------------------
// Weight repack kernels: make the per-(p,q)/(r,s) slices contiguous.
// W1 (C,F,H1,3,4)  -> W1r[(c*12+pq)*F*H1 + f*H1 + i]
// W2 (C,H1,H2,3,4) -> W2r[(c*12+rs)*H1*H2 + i*H2 + o]
// ---------------------------------------------------------------------------
__global__ void repack_w1_kernel(const float* __restrict__ W1, float* __restrict__ W1r) {
    int idx = blockIdx.x * 256 + threadIdx.x;
    const int total = C_ * 12 * F_ * H1_;
    if (idx >= total) return;
    int i  = idx % H1_;
    int f  = (idx / H1_) % F_;
    int pq = (idx / (H1_ * F_)) % 12;
    int c  = idx / (H1_ * F_ * 12);
    W1r[idx] = W1[(((size_t)c * F_ + f) * H1_ + i) * 12 + pq];
}

__global__ void repack_w2_kernel(const float* __restrict__ W2, float* __restrict__ W2r) {
    int idx = blockIdx.x * 256 + threadIdx.x;
    const int total = C_ * 12 * H1_ * H2_;
    if (idx >= total) return;
    int o  = idx % H2_;
    int i  = (idx / H2_) % H1_;
    int rs = (idx / (H2_ * H1_)) % 12;
    int c  = idx / (H2_ * H1_ * 12);
    W2r[idx] = W2[(((size_t)c * H1_ + i) * H2_ + o) * 12 + rs];
}

// ---------------------------------------------------------------------------
// Fused decoder: one block per (b, pq). Computes h1[:, :, p, q] (60x128) into
// LDS, then for each (r,s) the layer-2 GEMM tile + layer-3 reduction+sigmoid.
// Fully fused: no global intermediates.
// ---------------------------------------------------------------------------
template<bool PACKED>
__global__ __launch_bounds__(256) void fused_decoder(
    const float* __restrict__ x,   const int* __restrict__ cam,
    const float* __restrict__ W1,  const float* __restrict__ b1,
    const float* __restrict__ W2,  const float* __restrict__ b2,
    const float* __restrict__ W3,  const float* __restrict__ b3,
    const float* __restrict__ W1r, const float* __restrict__ W2r,
    float* __restrict__ out)
{
    __shared__ float h1s[T_ * H1_];   // 60*128 = 30720 B
    __shared__ float stage[8192];     // 32 KB: phase1 xs[32][64]+w1s[32][128]; phase2 w2s[128][64]

    const int pq  = blockIdx.x;       // 0..11
    const int b   = blockIdx.y;       // 0..127
    const int p   = pq >> 2, q = pq & 3;
    const int tid = threadIdx.x;
    const int c   = cam[b];

    float* xs  = stage;               // [32][64] (row pad to 64)
    float* w1s = stage + 2048;        // [32][128]

    // ------------------ Phase 1: h1 = relu(x^T * W1slice + b1) -------------
    const int ig = tid & 31;          // i-group: i = ig*4 .. ig*4+3
    const int tg = tid >> 5;          // t-group: t = tg*8 .. tg*8+7

    float acc[8][4];
    #pragma unroll
    for (int a = 0; a < 8; ++a)
        #pragma unroll
        for (int j = 0; j < 4; ++j) acc[a][j] = 0.f;

    for (int f0 = 0; f0 < F_; f0 += 32) {
        __syncthreads();
        // stage x chunk: xs[kk][t], t contiguous
        {
            int lane = tid & 63;
            int sub  = tid >> 6;
            if (lane < T_) {
                #pragma unroll
                for (int m = 0; m < 8; ++m) {
                    int kk = sub * 8 + m;
                    xs[kk * 64 + lane] = x[((size_t)b * F_ + f0 + kk) * T_ + lane];
                }
            }
        }
        // stage W1 chunk: w1s[kk][i]
        if (PACKED) {
            const float4* src = (const float4*)(W1r + ((size_t)(c * 12 + pq) * F_ + f0) * H1_);
            float4* dst = (float4*)w1s;
            #pragma unroll
            for (int m = 0; m < 4; ++m) dst[tid + m * 256] = src[tid + m * 256];
        } else {
            for (int e = tid; e < 32 * H1_; e += 256) {
                int kk = e >> 7, i = e & 127;
                w1s[e] = W1[(((size_t)c * F_ + f0 + kk) * H1_ + i) * 12 + pq];
            }
        }
        __syncthreads();
        #pragma unroll 8
        for (int kk = 0; kk < 32; ++kk) {
            float4 bv = *(const float4*)&w1s[kk * 128 + ig * 4];
            float4 a0 = *(const float4*)&xs[kk * 64 + tg * 8];
            float4 a1 = *(const float4*)&xs[kk * 64 + tg * 8 + 4];
            float at[8] = {a0.x, a0.y, a0.z, a0.w, a1.x, a1.y, a1.z, a1.w};
            #pragma unroll
            for (int tt = 0; tt < 8; ++tt) {
                acc[tt][0] = fmaf(at[tt], bv.x, acc[tt][0]);
                acc[tt][1] = fmaf(at[tt], bv.y, acc[tt][1]);
                acc[tt][2] = fmaf(at[tt], bv.z, acc[tt][2]);
                acc[tt][3] = fmaf(at[tt], bv.w, acc[tt][3]);
            }
        }
    }
    // bias + relu -> h1s
    {
        float4 b1v = *(const float4*)&b1[c * H1_ + ig * 4];
        #pragma unroll
        for (int tt = 0; tt < 8; ++tt) {
            int t = tg * 8 + tt;
            if (t < T_) {
                float4 hv;
                hv.x = fmaxf(acc[tt][0] + b1v.x, 0.f);
                hv.y = fmaxf(acc[tt][1] + b1v.y, 0.f);
                hv.z = fmaxf(acc[tt][2] + b1v.z, 0.f);
                hv.w = fmaxf(acc[tt][3] + b1v.w, 0.f);
                *(float4*)&h1s[t * H1_ + ig * 4] = hv;
            }
        }
    }

    // ------------------ Phase 2: layer2 GEMM + layer3 reduce ---------------
    const int lane = tid & 63;        // = o
    const int wv   = tid >> 6;        // wave -> t block of 15
    const float w3v = W3[c * H2_ + lane];
    const float b2v = b2[c * H2_ + lane];
    const float b3v = b3[c];
    float* w2s = stage;               // [128][64]

    for (int rs = 0; rs < 12; ++rs) {
        __syncthreads();              // protects stage reuse + h1s visibility (first iter)
        if (PACKED) {
            const float4* src = (const float4*)(W2r + (size_t)(c * 12 + rs) * H1_ * H2_);
            float4* dst = (float4*)w2s;
            #pragma unroll
            for (int m = 0; m < 8; ++m) dst[tid + m * 256] = src[tid + m * 256];
        } else {
            for (int e = tid; e < H1_ * H2_; e += 256) {
                int i = e >> 6, o = e & 63;
                w2s[e] = W2[(((size_t)c * H1_ + i) * H2_ + o) * 12 + rs];
            }
        }
        __syncthreads();

        float acc2[15];
        #pragma unroll
        for (int j = 0; j < 15; ++j) acc2[j] = 0.f;

        for (int i = 0; i < H1_; i += 4) {
            float wa = w2s[(i + 0) * 64 + lane];
            float wb = w2s[(i + 1) * 64 + lane];
            float wc = w2s[(i + 2) * 64 + lane];
            float wd = w2s[(i + 3) * 64 + lane];
            #pragma unroll
            for (int j = 0; j < 15; ++j) {
                float4 h = *(const float4*)&h1s[(wv * 15 + j) * H1_ + i];
                acc2[j] = fmaf(h.x, wa, acc2[j]);
                acc2[j] = fmaf(h.y, wb, acc2[j]);
                acc2[j] = fmaf(h.z, wc, acc2[j]);
                acc2[j] = fmaf(h.w, wd, acc2[j]);
            }
        }

        const int r = rs >> 2, s = rs & 3;
        const int hrow = p * 3 + r, wcol = q * 4 + s;
        #pragma unroll
        for (int j = 0; j < 15; ++j) {
            float y = w3v * fmaxf(acc2[j] + b2v, 0.f);
            #pragma unroll
            for (int m = 32; m > 0; m >>= 1) y += __shfl_xor(y, m, 64);
            if (lane == j) {
                int t = wv * 15 + j;
                float v = y + b3v;
                out[(((size_t)b * T_ + t) * 9 + hrow) * 16 + wcol] = 1.f / (1.f + __expf(-v));
            }
        }
    }
}

// ---------------------------------------------------------------------------
extern "C" void kernel_launch(void* const* d_in, const int* in_sizes, int n_in,
                              void* d_out, int out_size, void* d_ws, size_t ws_size,
                              hipStream_t stream) {
    const float* x   = (const float*)d_in[0];
    const int*   cam = (const int*)  d_in[1];
    const float* W1  = (const float*)d_in[2];
    const float* b1  = (const float*)d_in[3];
    const float* W2  = (const float*)d_in[4];
    const float* b2  = (const float*)d_in[5];
    const float* W3  = (const float*)d_in[6];
    const float* b3  = (const float*)d_in[7];
    float* out = (float*)d_out;

    const size_t n_w1 = (size_t)C_ * 12 * F_ * H1_;   // 11,796,480
    const size_t n_w2 = (size_t)C_ * 12 * H1_ * H2_;  // 1,474,560
    const size_t needed = (n_w1 + n_w2) * sizeof(float);

    if (d_ws != nullptr && ws_size >= needed) {
        float* W1r = (float*)d_ws;
        float* W2r = W1r + n_w1;
        repack_w1_kernel<<<(int)((n_w1 + 255) / 256), 256, 0, stream>>>(W1, W1r);
        repack_w2_kernel<<<(int)((n_w2 + 255) / 256), 256, 0, stream>>>(W2, W2r);
        fused_decoder<true><<<dim3(12, B_), 256, 0, stream>>>(
            x, cam, W1, b1, W2, b2, W3, b3, W1r, W2r, out);
    } else {
        fused_decoder<false><<<dim3(12, B_), 256, 0, stream>>>(
            x, cam, W1, b1, W2, b2, W3, b3, nullptr, nullptr, out);
    }
}

// Round 2
// 173.849 us; speedup vs baseline: 4.7948x; 4.7948x over previous
//
#include <hip/hip_runtime.h>
#include <hip/hip_bf16.h>
#include <cstdint>

// Problem constants
#define B_  128
#define F_  512
#define T_  60
#define C_  15
#define H1_ 128
#define H2_ 64

typedef short short8_t __attribute__((ext_vector_type(8)));   // 8 bf16 (4 VGPR)
typedef float f32x4    __attribute__((ext_vector_type(4)));   // MFMA acc

static __device__ __forceinline__ unsigned short f2bf(float f) {
    union { float f; uint32_t u; } v; v.f = f;
    uint32_t r = v.u + 0x7FFF + ((v.u >> 16) & 1);   // RNE
    return (unsigned short)(r >> 16);
}

// ---------------------------------------------------------------------------
// Repack x (B,F,T) f32 -> xT (B,64,F) bf16, t padded 60->64 with zeros.
// ---------------------------------------------------------------------------
__global__ __launch_bounds__(256) void repack_x(const float* __restrict__ x,
                                                unsigned short* __restrict__ xT) {
    __shared__ float xs[128][61];
    const int b = blockIdx.x, tid = threadIdx.x;
    for (int f0 = 0; f0 < F_; f0 += 128) {
        __syncthreads();
        #pragma unroll
        for (int it = 0; it < 32; ++it) {
            int idx = tid + it * 256;          // 128*64
            int fl = idx >> 6, t = idx & 63;
            if (t < T_) xs[fl][t] = x[((size_t)b * F_ + f0 + fl) * T_ + t];
        }
        __syncthreads();
        #pragma unroll
        for (int it = 0; it < 8; ++it) {
            int idx = tid + it * 256;          // 64*32
            int t = idx >> 5, f4 = (idx & 31) * 4;
            ushort4 o;
            o.x = (t < T_) ? f2bf(xs[f4 + 0][t]) : 0;
            o.y = (t < T_) ? f2bf(xs[f4 + 1][t]) : 0;
            o.z = (t < T_) ? f2bf(xs[f4 + 2][t]) : 0;
            o.w = (t < T_) ? f2bf(xs[f4 + 3][t]) : 0;
            *(ushort4*)(xT + ((size_t)b * 64 + t) * F_ + f0 + f4) = o;
        }
    }
}

// ---------------------------------------------------------------------------
// Repack W1 (C,F,H1,3,4) f32 -> W1b[(c*12+pq)][i][f] bf16  ([n][k], B^T form)
// block = (f-block 32, i-block 32, c)
// ---------------------------------------------------------------------------
__global__ __launch_bounds__(256) void repack_w1(const float* __restrict__ W1,
                                                 unsigned short* __restrict__ W1b) {
    __shared__ float ls[32][384];
    const int f0 = blockIdx.x * 32, i0 = blockIdx.y * 32, c = blockIdx.z;
    const int tid = threadIdx.x;
    #pragma unroll
    for (int it = 0; it < 12; ++it) {
        int idx = tid + it * 256;              // 3072 float4
        int fl = idx / 96, r = idx - fl * 96;
        float4 v = *(const float4*)(W1 + ((size_t)(c * F_ + f0 + fl)) * (H1_ * 12)
                                       + (size_t)i0 * 12 + r * 4);
        *(float4*)&ls[fl][r * 4] = v;
    }
    __syncthreads();
    const int i_l = tid >> 3, f_l = (tid & 7) * 4;
    #pragma unroll
    for (int pq = 0; pq < 12; ++pq) {
        ushort4 o;
        o.x = f2bf(ls[f_l + 0][i_l * 12 + pq]);
        o.y = f2bf(ls[f_l + 1][i_l * 12 + pq]);
        o.z = f2bf(ls[f_l + 2][i_l * 12 + pq]);
        o.w = f2bf(ls[f_l + 3][i_l * 12 + pq]);
        *(ushort4*)(W1b + (((size_t)(c * 12 + pq)) * H1_ + i0 + i_l) * F_ + f0 + f_l) = o;
    }
}

// ---------------------------------------------------------------------------
// Repack W2 (C,H1,H2,3,4) f32 -> W2b[(c*12+rs)][o][i] bf16
// block = (i-block 32, o-block 32, c)
// ---------------------------------------------------------------------------
__global__ __launch_bounds__(256) void repack_w2(const float* __restrict__ W2,
                                                 unsigned short* __restrict__ W2b) {
    __shared__ float ls[32][384];
    const int i0 = blockIdx.x * 32, o0 = blockIdx.y * 32, c = blockIdx.z;
    const int tid = threadIdx.x;
    #pragma unroll
    for (int it = 0; it < 12; ++it) {
        int idx = tid + it * 256;
        int il = idx / 96, r = idx - il * 96;
        float4 v = *(const float4*)(W2 + ((size_t)(c * H1_ + i0 + il)) * (H2_ * 12)
                                       + (size_t)o0 * 12 + r * 4);
        *(float4*)&ls[il][r * 4] = v;
    }
    __syncthreads();
    const int o_l = tid >> 3, i_l = (tid & 7) * 4;
    #pragma unroll
    for (int rs = 0; rs < 12; ++rs) {
        ushort4 o;
        o.x = f2bf(ls[i_l + 0][o_l * 12 + rs]);
        o.y = f2bf(ls[i_l + 1][o_l * 12 + rs]);
        o.z = f2bf(ls[i_l + 2][o_l * 12 + rs]);
        o.w = f2bf(ls[i_l + 3][o_l * 12 + rs]);
        *(ushort4*)(W2b + (((size_t)(c * 12 + rs)) * H2_ + o0 + o_l) * H1_ + i0 + i_l) = o;
    }
}

// ---------------------------------------------------------------------------
// Fused MFMA decoder. Block = (pq, b), 256 threads = 4 waves.
// Phase1: h1(64x128) = xT(64x512) * W1b^T via mfma_16x16x32_bf16; A,B direct
//   from global (L2-hot), wave w owns n-cols 32w..32w+31. h1 -> LDS (bf16).
// Phase2: each wave owns 3 whole rs GEMMs (64x64,K=128), A hoisted from LDS,
//   B direct from global; layer-3 reduce + sigmoid wave-locally.
// ---------------------------------------------------------------------------
__global__ __launch_bounds__(256) void fused_mfma(
    const unsigned short* __restrict__ xT, const unsigned short* __restrict__ W1b,
    const unsigned short* __restrict__ W2b, const int* __restrict__ cam,
    const float* __restrict__ b1, const float* __restrict__ b2,
    const float* __restrict__ W3, const float* __restrict__ b3,
    float* __restrict__ out)
{
    __shared__ unsigned short h1s[64 * 136];   // [t][i], stride 136 (bank-rotating)

    const int pq = blockIdx.x, b = blockIdx.y;
    const int tid = threadIdx.x;
    const int w = tid >> 6, l = tid & 63;
    const int l15 = l & 15, g = l >> 4;
    const int c = cam[b];

    // ---------------- Phase 1 ----------------
    const unsigned short* Ap = xT + (size_t)b * (64 * F_) + (size_t)l15 * F_ + 8 * g;
    const unsigned short* Bp = W1b + ((size_t)(c * 12 + pq) * H1_ + 32 * w + l15) * F_ + 8 * g;

    f32x4 acc1[4][2];
    #pragma unroll
    for (int mt = 0; mt < 4; ++mt) {
        acc1[mt][0] = (f32x4){0.f, 0.f, 0.f, 0.f};
        acc1[mt][1] = (f32x4){0.f, 0.f, 0.f, 0.f};
    }

    short8_t af[2][4], bf[2][2];
    #pragma unroll
    for (int mt = 0; mt < 4; ++mt) af[0][mt] = *(const short8_t*)(Ap + mt * (16 * F_));
    bf[0][0] = *(const short8_t*)(Bp);
    bf[0][1] = *(const short8_t*)(Bp + 16 * F_);

    #pragma unroll
    for (int kk = 0; kk < 16; ++kk) {
        const int cur = kk & 1, nxt = cur ^ 1;
        if (kk < 15) {
            const int ko = (kk + 1) * 32;
            #pragma unroll
            for (int mt = 0; mt < 4; ++mt)
                af[nxt][mt] = *(const short8_t*)(Ap + mt * (16 * F_) + ko);
            bf[nxt][0] = *(const short8_t*)(Bp + ko);
            bf[nxt][1] = *(const short8_t*)(Bp + 16 * F_ + ko);
        }
        #pragma unroll
        for (int mt = 0; mt < 4; ++mt)
            #pragma unroll
            for (int ni = 0; ni < 2; ++ni)
                acc1[mt][ni] = __builtin_amdgcn_mfma_f32_16x16x32_bf16(
                    af[cur][mt], bf[cur][ni], acc1[mt][ni], 0, 0, 0);
    }

    // bias + relu -> h1s (C layout: row t = 16mt+4g+r, col i = 32w+16ni+l15)
    #pragma unroll
    for (int ni = 0; ni < 2; ++ni) {
        const int i = 32 * w + 16 * ni + l15;
        const float b1v = b1[c * H1_ + i];
        #pragma unroll
        for (int mt = 0; mt < 4; ++mt)
            #pragma unroll
            for (int r = 0; r < 4; ++r) {
                float h = acc1[mt][ni][r] + b1v;
                h = h > 0.f ? h : 0.f;
                h1s[(16 * mt + 4 * g + r) * 136 + i] = f2bf(h);
            }
    }
    __syncthreads();

    // ---------------- Phase 2 ----------------
    // hoist A fragments: a2[mt][kk] = h1[16mt+l15][32kk+8g ..+8]
    short8_t a2[4][4];
    #pragma unroll
    for (int mt = 0; mt < 4; ++mt)
        #pragma unroll
        for (int kk = 0; kk < 4; ++kk)
            a2[mt][kk] = *(const short8_t*)&h1s[(16 * mt + l15) * 136 + 32 * kk + 8 * g];

    float w3v[4], b2v[4];
    #pragma unroll
    for (int nt = 0; nt < 4; ++nt) {
        w3v[nt] = W3[c * H2_ + 16 * nt + l15];
        b2v[nt] = b2[c * H2_ + 16 * nt + l15];
    }
    const float b3v = b3[c];
    const int p = pq >> 2, q = pq & 3;

    for (int rr = 0; rr < 3; ++rr) {
        const int rs = w * 3 + rr;
        const unsigned short* B2 =
            W2b + ((size_t)(c * 12 + rs) * H2_ + l15) * H1_ + 8 * g;

        float s[4][4];
        #pragma unroll
        for (int mt = 0; mt < 4; ++mt) { s[mt][0] = s[mt][1] = s[mt][2] = s[mt][3] = 0.f; }

        #pragma unroll
        for (int nt = 0; nt < 4; ++nt) {
            short8_t bfr[4];
            #pragma unroll
            for (int kk = 0; kk < 4; ++kk)
                bfr[kk] = *(const short8_t*)(B2 + nt * (16 * H1_) + kk * 32);
            #pragma unroll
            for (int mt = 0; mt < 4; ++mt) {
                f32x4 acc2 = (f32x4){0.f, 0.f, 0.f, 0.f};
                #pragma unroll
                for (int kk = 0; kk < 4; ++kk)
                    acc2 = __builtin_amdgcn_mfma_f32_16x16x32_bf16(
                        a2[mt][kk], bfr[kk], acc2, 0, 0, 0);
                #pragma unroll
                for (int r = 0; r < 4; ++r)
                    s[mt][r] += w3v[nt] * fmaxf(acc2[r] + b2v[nt], 0.f);
            }
        }

        const int hrow = p * 3 + (rs >> 2), wcol = q * 4 + (rs & 3);
        #pragma unroll
        for (int mt = 0; mt < 4; ++mt)
            #pragma unroll
            for (int r = 0; r < 4; ++r) {
                float v = s[mt][r];
                v += __shfl_xor(v, 1); v += __shfl_xor(v, 2);
                v += __shfl_xor(v, 4); v += __shfl_xor(v, 8);
                if (l15 == 0) {
                    const int t = 16 * mt + 4 * g + r;
                    if (t < T_)
                        out[(((size_t)b * T_ + t) * 9 + hrow) * 16 + wcol] =
                            1.f / (1.f + __expf(-(v + b3v)));
                }
            }
    }
}

// ---------------------------------------------------------------------------
// fp32 VALU fallback (round-1 kernel, unpacked path) — used only if ws too small
// ---------------------------------------------------------------------------
__global__ __launch_bounds__(256) void fused_decoder_f32(
    const float* __restrict__ x,   const int* __restrict__ cam,
    const float* __restrict__ W1,  const float* __restrict__ b1,
    const float* __restrict__ W2,  const float* __restrict__ b2,
    const float* __restrict__ W3,  const float* __restrict__ b3,
    float* __restrict__ out)
{
    __shared__ float h1s[T_ * H1_];
    __shared__ float stage[8192];

    const int pq  = blockIdx.x;
    const int b   = blockIdx.y;
    const int p   = pq >> 2, q = pq & 3;
    const int tid = threadIdx.x;
    const int c   = cam[b];

    float* xs  = stage;
    float* w1s = stage + 2048;

    const int ig = tid & 31;
    const int tg = tid >> 5;

    float acc[8][4];
    #pragma unroll
    for (int a = 0; a < 8; ++a)
        #pragma unroll
        for (int j = 0; j < 4; ++j) acc[a][j] = 0.f;

    for (int f0 = 0; f0 < F_; f0 += 32) {
        __syncthreads();
        {
            int lane = tid & 63;
            int sub  = tid >> 6;
            if (lane < T_) {
                #pragma unroll
                for (int m = 0; m < 8; ++m) {
                    int kk = sub * 8 + m;
                    xs[kk * 64 + lane] = x[((size_t)b * F_ + f0 + kk) * T_ + lane];
                }
            }
        }
        for (int e = tid; e < 32 * H1_; e += 256) {
            int kk = e >> 7, i = e & 127;
            w1s[e] = W1[(((size_t)c * F_ + f0 + kk) * H1_ + i) * 12 + pq];
        }
        __syncthreads();
        #pragma unroll 8
        for (int kk = 0; kk < 32; ++kk) {
            float4 bv = *(const float4*)&w1s[kk * 128 + ig * 4];
            float4 a0 = *(const float4*)&xs[kk * 64 + tg * 8];
            float4 a1 = *(const float4*)&xs[kk * 64 + tg * 8 + 4];
            float at[8] = {a0.x, a0.y, a0.z, a0.w, a1.x, a1.y, a1.z, a1.w};
            #pragma unroll
            for (int tt = 0; tt < 8; ++tt) {
                acc[tt][0] = fmaf(at[tt], bv.x, acc[tt][0]);
                acc[tt][1] = fmaf(at[tt], bv.y, acc[tt][1]);
                acc[tt][2] = fmaf(at[tt], bv.z, acc[tt][2]);
                acc[tt][3] = fmaf(at[tt], bv.w, acc[tt][3]);
            }
        }
    }
    {
        float4 b1v = *(const float4*)&b1[c * H1_ + ig * 4];
        #pragma unroll
        for (int tt = 0; tt < 8; ++tt) {
            int t = tg * 8 + tt;
            if (t < T_) {
                float4 hv;
                hv.x = fmaxf(acc[tt][0] + b1v.x, 0.f);
                hv.y = fmaxf(acc[tt][1] + b1v.y, 0.f);
                hv.z = fmaxf(acc[tt][2] + b1v.z, 0.f);
                hv.w = fmaxf(acc[tt][3] + b1v.w, 0.f);
                *(float4*)&h1s[t * H1_ + ig * 4] = hv;
            }
        }
    }

    const int lane = tid & 63;
    const int wv   = tid >> 6;
    const float w3v = W3[c * H2_ + lane];
    const float b2v = b2[c * H2_ + lane];
    const float b3v = b3[c];
    float* w2s = stage;

    for (int rs = 0; rs < 12; ++rs) {
        __syncthreads();
        for (int e = tid; e < H1_ * H2_; e += 256) {
            int i = e >> 6, o = e & 63;
            w2s[e] = W2[(((size_t)c * H1_ + i) * H2_ + o) * 12 + rs];
        }
        __syncthreads();

        float acc2[15];
        #pragma unroll
        for (int j = 0; j < 15; ++j) acc2[j] = 0.f;

        for (int i = 0; i < H1_; i += 4) {
            float wa = w2s[(i + 0) * 64 + lane];
            float wb = w2s[(i + 1) * 64 + lane];
            float wc = w2s[(i + 2) * 64 + lane];
            float wd = w2s[(i + 3) * 64 + lane];
            #pragma unroll
            for (int j = 0; j < 15; ++j) {
                float4 h = *(const float4*)&h1s[(wv * 15 + j) * H1_ + i];
                acc2[j] = fmaf(h.x, wa, acc2[j]);
                acc2[j] = fmaf(h.y, wb, acc2[j]);
                acc2[j] = fmaf(h.z, wc, acc2[j]);
                acc2[j] = fmaf(h.w, wd, acc2[j]);
            }
        }

        const int r = rs >> 2, s = rs & 3;
        const int hrow = p * 3 + r, wcol = q * 4 + s;
        #pragma unroll
        for (int j = 0; j < 15; ++j) {
            float y = w3v * fmaxf(acc2[j] + b2v, 0.f);
            #pragma unroll
            for (int m = 32; m > 0; m >>= 1) y += __shfl_xor(y, m, 64);
            if (lane == j) {
                int t = wv * 15 + j;
                float v = y + b3v;
                out[(((size_t)b * T_ + t) * 9 + hrow) * 16 + wcol] = 1.f / (1.f + __expf(-v));
            }
        }
    }
}

// ---------------------------------------------------------------------------
extern "C" void kernel_launch(void* const* d_in, const int* in_sizes, int n_in,
                              void* d_out, int out_size, void* d_ws, size_t ws_size,
                              hipStream_t stream) {
    const float* x   = (const float*)d_in[0];
    const int*   cam = (const int*)  d_in[1];
    const float* W1  = (const float*)d_in[2];
    const float* b1  = (const float*)d_in[3];
    const float* W2  = (const float*)d_in[4];
    const float* b2  = (const float*)d_in[5];
    const float* W3  = (const float*)d_in[6];
    const float* b3  = (const float*)d_in[7];
    float* outp = (float*)d_out;

    const size_t n_xT  = (size_t)B_ * 64 * F_;          //  4,194,304
    const size_t n_w1b = (size_t)C_ * 12 * H1_ * F_;    // 11,796,480
    const size_t n_w2b = (size_t)C_ * 12 * H2_ * H1_;   //  1,474,560
    const size_t needed = (n_xT + n_w1b + n_w2b) * sizeof(unsigned short);

    if (d_ws != nullptr && ws_size >= needed) {
        unsigned short* xT  = (unsigned short*)d_ws;
        unsigned short* W1p = xT + n_xT;
        unsigned short* W2p = W1p + n_w1b;
        repack_x <<<B_, 256, 0, stream>>>(x, xT);
        repack_w1<<<dim3(F_ / 32, H1_ / 32, C_), 256, 0, stream>>>(W1, W1p);
        repack_w2<<<dim3(H1_ / 32, H2_ / 32, C_), 256, 0, stream>>>(W2, W2p);
        fused_mfma<<<dim3(12, B_), 256, 0, stream>>>(
            xT, W1p, W2p, cam, b1, b2, W3, b3, outp);
    } else {
        fused_decoder_f32<<<dim3(12, B_), 256, 0, stream>>>(
            x, cam, W1, b1, W2, b2, W3, b3, outp);
    }
}

// Round 3
// 146.462 us; speedup vs baseline: 5.6914x; 1.1870x over previous
//
#include <hip/hip_runtime.h>
#include <hip/hip_bf16.h>
#include <cstdint>

// Problem constants
#define B_  128
#define F_  512
#define T_  60
#define C_  15
#define H1_ 128
#define H2_ 64

typedef short short8_t __attribute__((ext_vector_type(8)));   // 8 bf16 (4 VGPR)
typedef float f32x4    __attribute__((ext_vector_type(4)));   // MFMA acc

static __device__ __forceinline__ unsigned short f2bf(float f) {
    union { float f; uint32_t u; } v; v.f = f;
    uint32_t r = v.u + 0x7FFF + ((v.u >> 16) & 1);   // RNE
    return (unsigned short)(r >> 16);
}

// async 16B global -> LDS DMA (dest = wave-uniform base + lane*16)
static __device__ __forceinline__ void async_cp16(const unsigned short* g, unsigned short* l) {
    __builtin_amdgcn_global_load_lds(
        (const __attribute__((address_space(1))) unsigned int*)g,
        (__attribute__((address_space(3))) unsigned int*)l, 16, 0, 0);
}

#define VMWAIT4() asm volatile("s_waitcnt vmcnt(4)" ::: "memory")
#define VMWAIT0() asm volatile("s_waitcnt vmcnt(0)" ::: "memory")

// ---------------------------------------------------------------------------
// Repack x (B,F,T) f32 -> xT (B,64,F) bf16, t padded 60->64 with zeros.
// grid (4 f-chunks, B)
// ---------------------------------------------------------------------------
__global__ __launch_bounds__(256) void repack_x(const float* __restrict__ x,
                                                unsigned short* __restrict__ xT) {
    __shared__ float xs[128][61];
    const int f0 = blockIdx.x * 128, b = blockIdx.y, tid = threadIdx.x;
    #pragma unroll
    for (int it = 0; it < 32; ++it) {
        int idx = tid + it * 256;          // 128*64
        int fl = idx >> 6, t = idx & 63;
        if (t < T_) xs[fl][t] = x[((size_t)b * F_ + f0 + fl) * T_ + t];
    }
    __syncthreads();
    #pragma unroll
    for (int it = 0; it < 8; ++it) {
        int idx = tid + it * 256;          // 64*32
        int t = idx >> 5, f4 = (idx & 31) * 4;
        ushort4 o;
        o.x = (t < T_) ? f2bf(xs[f4 + 0][t]) : 0;
        o.y = (t < T_) ? f2bf(xs[f4 + 1][t]) : 0;
        o.z = (t < T_) ? f2bf(xs[f4 + 2][t]) : 0;
        o.w = (t < T_) ? f2bf(xs[f4 + 3][t]) : 0;
        *(ushort4*)(xT + ((size_t)b * 64 + t) * F_ + f0 + f4) = o;
    }
}

// ---------------------------------------------------------------------------
// Repack W1 (C,F,H1,3,4) f32 -> W1b[(c*12+pq)][i][f] bf16  ([n][k], B^T form)
// ---------------------------------------------------------------------------
__global__ __launch_bounds__(256) void repack_w1(const float* __restrict__ W1,
                                                 unsigned short* __restrict__ W1b) {
    __shared__ float ls[32][384];
    const int f0 = blockIdx.x * 32, i0 = blockIdx.y * 32, c = blockIdx.z;
    const int tid = threadIdx.x;
    #pragma unroll
    for (int it = 0; it < 12; ++it) {
        int idx = tid + it * 256;              // 3072 float4
        int fl = idx / 96, r = idx - fl * 96;
        float4 v = *(const float4*)(W1 + ((size_t)(c * F_ + f0 + fl)) * (H1_ * 12)
                                       + (size_t)i0 * 12 + r * 4);
        *(float4*)&ls[fl][r * 4] = v;
    }
    __syncthreads();
    const int i_l = tid >> 3, f_l = (tid & 7) * 4;
    #pragma unroll
    for (int pq = 0; pq < 12; ++pq) {
        ushort4 o;
        o.x = f2bf(ls[f_l + 0][i_l * 12 + pq]);
        o.y = f2bf(ls[f_l + 1][i_l * 12 + pq]);
        o.z = f2bf(ls[f_l + 2][i_l * 12 + pq]);
        o.w = f2bf(ls[f_l + 3][i_l * 12 + pq]);
        *(ushort4*)(W1b + (((size_t)(c * 12 + pq)) * H1_ + i0 + i_l) * F_ + f0 + f_l) = o;
    }
}

// ---------------------------------------------------------------------------
// Repack W2 (C,H1,H2,3,4) f32 -> W2b[(c*12+rs)][o][i] bf16
// ---------------------------------------------------------------------------
__global__ __launch_bounds__(256) void repack_w2(const float* __restrict__ W2,
                                                 unsigned short* __restrict__ W2b) {
    __shared__ float ls[32][384];
    const int i0 = blockIdx.x * 32, o0 = blockIdx.y * 32, c = blockIdx.z;
    const int tid = threadIdx.x;
    #pragma unroll
    for (int it = 0; it < 12; ++it) {
        int idx = tid + it * 256;
        int il = idx / 96, r = idx - il * 96;
        float4 v = *(const float4*)(W2 + ((size_t)(c * H1_ + i0 + il)) * (H2_ * 12)
                                       + (size_t)o0 * 12 + r * 4);
        *(float4*)&ls[il][r * 4] = v;
    }
    __syncthreads();
    const int o_l = tid >> 3, i_l = (tid & 7) * 4;
    #pragma unroll
    for (int rs = 0; rs < 12; ++rs) {
        ushort4 o;
        o.x = f2bf(ls[i_l + 0][o_l * 12 + rs]);
        o.y = f2bf(ls[i_l + 1][o_l * 12 + rs]);
        o.z = f2bf(ls[i_l + 2][o_l * 12 + rs]);
        o.w = f2bf(ls[i_l + 3][o_l * 12 + rs]);
        *(ushort4*)(W2b + (((size_t)(c * 12 + rs)) * H2_ + o0 + o_l) * H1_ + i0 + i_l) = o;
    }
}

// ---------------------------------------------------------------------------
// Fused MFMA decoder, pipelined.
// 1536 blocks (XCD-swizzled), 256 threads = 4 waves.
// Phase1: h1(64x128) = xT(64x512) * W1b^T. B staged per-wave via
//   global_load_lds into 3 rotating LDS buffers (2 k-steps ahead, counted
//   vmcnt, NO barriers in K-loop; XOR-swizzled via pre-swizzled source).
//   A direct global->reg, 1 step ahead (L2-hot: 12 sibling blocks share xT).
// Phase2: per-wave 3 rs GEMMs, B 1-segment-ahead reg prefetch (W2b L2-hot).
// ---------------------------------------------------------------------------
__global__ __launch_bounds__(256, 3) void fused_mfma(
    const unsigned short* __restrict__ xT, const unsigned short* __restrict__ W1b,
    const unsigned short* __restrict__ W2b, const int* __restrict__ cam,
    const float* __restrict__ b1, const float* __restrict__ b2,
    const float* __restrict__ W3, const float* __restrict__ b3,
    float* __restrict__ out)
{
    // 3 B-buffers [3][128 rows][64 bf16] = 48KB; h1s (17408B) unioned on top.
    __shared__ __align__(16) unsigned char smem[49152];

    const int idx = blockIdx.x;
    const int swz = (idx & 7) * 192 + (idx >> 3);   // bijective XCD swizzle
    const int b = swz / 12, pq = swz - (swz / 12) * 12;

    const int tid = threadIdx.x;
    const int w = tid >> 6, l = tid & 63;
    const int l15 = l & 15, g = l >> 4;
    const int c = cam[b];

    // ---------------- Phase 1 ----------------
    const unsigned short* Ap = xT + (size_t)b * (64 * F_) + (size_t)l15 * F_ + 8 * g;
    // staging source (pre-swizzled column so linear LDS dest ends up swizzled):
    // lane l handles row (w*32 + j*8 + (l>>3)), src col16 = (l&7) ^ (l>>3)
    const unsigned short* Bsrc0 = W1b + (size_t)(c * 12 + pq) * (H1_ * F_)
                                + (size_t)(w * 32 + (l >> 3)) * F_
                                + (((l & 7) ^ (l >> 3)) * 8);
    const int ldsw = w * 4096;   // wave-uniform byte offset of this wave's rows

    // prologue: stage k-steps 0,1; load A step 0
    #pragma unroll
    for (int j = 0; j < 4; ++j)
        async_cp16(Bsrc0 + j * (8 * F_), (unsigned short*)(smem + 0 * 16384 + ldsw + j * 1024));
    #pragma unroll
    for (int j = 0; j < 4; ++j)
        async_cp16(Bsrc0 + j * (8 * F_) + 64, (unsigned short*)(smem + 1 * 16384 + ldsw + j * 1024));

    short8_t af[2][8];
    #pragma unroll
    for (int mt = 0; mt < 4; ++mt)
        #pragma unroll
        for (int kk2 = 0; kk2 < 2; ++kk2)
            af[0][mt * 2 + kk2] = *(const short8_t*)(Ap + mt * (16 * F_) + kk2 * 32);

    f32x4 acc1[4][2];
    #pragma unroll
    for (int mt = 0; mt < 4; ++mt) {
        acc1[mt][0] = (f32x4){0.f, 0.f, 0.f, 0.f};
        acc1[mt][1] = (f32x4){0.f, 0.f, 0.f, 0.f};
    }

    #pragma unroll
    for (int ks = 0; ks < 8; ++ks) {
        if (ks < 7) { VMWAIT4(); } else { VMWAIT0(); }

        // ds_read this step's 4 B fragments (swizzled addressing)
        short8_t bfr1[2][2];
        #pragma unroll
        for (int kk2 = 0; kk2 < 2; ++kk2)
            #pragma unroll
            for (int ni = 0; ni < 2; ++ni) {
                const int i = 32 * w + 16 * ni + l15;
                const int c16 = (kk2 * 4 + g) ^ (l15 & 7);
                bfr1[kk2][ni] = *(const short8_t*)(smem + (ks % 3) * 16384 + i * 128 + c16 * 16);
            }

        // A prefetch (1 step ahead)
        if (ks < 7) {
            #pragma unroll
            for (int mt = 0; mt < 4; ++mt)
                #pragma unroll
                for (int kk2 = 0; kk2 < 2; ++kk2)
                    af[(ks + 1) & 1][mt * 2 + kk2] =
                        *(const short8_t*)(Ap + mt * (16 * F_) + (ks + 1) * 64 + kk2 * 32);
        }
        // B stage (2 steps ahead)
        if (ks < 6) {
            #pragma unroll
            for (int j = 0; j < 4; ++j)
                async_cp16(Bsrc0 + j * (8 * F_) + (ks + 2) * 64,
                           (unsigned short*)(smem + ((ks + 2) % 3) * 16384 + ldsw + j * 1024));
        }

        #pragma unroll
        for (int kk2 = 0; kk2 < 2; ++kk2)
            #pragma unroll
            for (int mt = 0; mt < 4; ++mt)
                #pragma unroll
                for (int ni = 0; ni < 2; ++ni)
                    acc1[mt][ni] = __builtin_amdgcn_mfma_f32_16x16x32_bf16(
                        af[ks & 1][mt * 2 + kk2], bfr1[kk2][ni], acc1[mt][ni], 0, 0, 0);
    }

    __syncthreads();   // all waves done reading B buffers before h1s overwrite

    // bias + relu -> h1s (C layout: row t = 16mt+4g+r, col i = 32w+16ni+l15)
    unsigned short* h1s = (unsigned short*)smem;   // [64][136]
    #pragma unroll
    for (int ni = 0; ni < 2; ++ni) {
        const int i = 32 * w + 16 * ni + l15;
        const float b1v = b1[c * H1_ + i];
        #pragma unroll
        for (int mt = 0; mt < 4; ++mt)
            #pragma unroll
            for (int r = 0; r < 4; ++r) {
                float h = acc1[mt][ni][r] + b1v;
                h = h > 0.f ? h : 0.f;
                h1s[(16 * mt + 4 * g + r) * 136 + i] = f2bf(h);
            }
    }
    __syncthreads();

    // ---------------- Phase 2 ----------------
    short8_t a2[4][4];
    #pragma unroll
    for (int mt = 0; mt < 4; ++mt)
        #pragma unroll
        for (int kk = 0; kk < 4; ++kk)
            a2[mt][kk] = *(const short8_t*)&h1s[(16 * mt + l15) * 136 + 32 * kk + 8 * g];

    float w3v[4], b2v[4];
    #pragma unroll
    for (int nt = 0; nt < 4; ++nt) {
        w3v[nt] = W3[c * H2_ + 16 * nt + l15];
        b2v[nt] = b2[c * H2_ + 16 * nt + l15];
    }
    const float b3v = b3[c];
    const int p = pq >> 2, q = pq & 3;

    const unsigned short* W2base = W2b + (size_t)(c * 12 + w * 3) * (H2_ * H1_)
                                 + (size_t)l15 * H1_ + 8 * g;
    // seg = 0..11 : rs_local = seg>>2, nt = seg&3
    short8_t bfr[2][4];
    #pragma unroll
    for (int kk = 0; kk < 4; ++kk)
        bfr[0][kk] = *(const short8_t*)(W2base + kk * 32);

    float s[4][4];
    #pragma unroll
    for (int mt = 0; mt < 4; ++mt) { s[mt][0] = s[mt][1] = s[mt][2] = s[mt][3] = 0.f; }

    #pragma unroll
    for (int seg = 0; seg < 12; ++seg) {
        if (seg < 11) {
            const int ns = seg + 1;
            const unsigned short* nb = W2base + (size_t)(ns >> 2) * (H2_ * H1_)
                                     + (ns & 3) * (16 * H1_);
            #pragma unroll
            for (int kk = 0; kk < 4; ++kk)
                bfr[(seg + 1) & 1][kk] = *(const short8_t*)(nb + kk * 32);
        }
        const int nt = seg & 3;
        #pragma unroll
        for (int mt = 0; mt < 4; ++mt) {
            f32x4 acc2 = (f32x4){0.f, 0.f, 0.f, 0.f};
            #pragma unroll
            for (int kk = 0; kk < 4; ++kk)
                acc2 = __builtin_amdgcn_mfma_f32_16x16x32_bf16(
                    a2[mt][kk], bfr[seg & 1][kk], acc2, 0, 0, 0);
            #pragma unroll
            for (int r = 0; r < 4; ++r)
                s[mt][r] += w3v[nt] * fmaxf(acc2[r] + b2v[nt], 0.f);
        }

        if (nt == 3) {
            const int rs = w * 3 + (seg >> 2);
            const int hrow = p * 3 + (rs >> 2), wcol = q * 4 + (rs & 3);
            #pragma unroll
            for (int mt = 0; mt < 4; ++mt)
                #pragma unroll
                for (int r = 0; r < 4; ++r) {
                    float v = s[mt][r];
                    v += __shfl_xor(v, 1); v += __shfl_xor(v, 2);
                    v += __shfl_xor(v, 4); v += __shfl_xor(v, 8);
                    if (l15 == 0) {
                        const int t = 16 * mt + 4 * g + r;
                        if (t < T_)
                            out[(((size_t)b * T_ + t) * 9 + hrow) * 16 + wcol] =
                                1.f / (1.f + __expf(-(v + b3v)));
                    }
                    s[mt][r] = 0.f;
                }
        }
    }
}

// ---------------------------------------------------------------------------
// fp32 VALU fallback — used only if ws too small
// ---------------------------------------------------------------------------
__global__ __launch_bounds__(256) void fused_decoder_f32(
    const float* __restrict__ x,   const int* __restrict__ cam,
    const float* __restrict__ W1,  const float* __restrict__ b1,
    const float* __restrict__ W2,  const float* __restrict__ b2,
    const float* __restrict__ W3,  const float* __restrict__ b3,
    float* __restrict__ out)
{
    __shared__ float h1s[T_ * H1_];
    __shared__ float stage[8192];

    const int pq  = blockIdx.x;
    const int b   = blockIdx.y;
    const int p   = pq >> 2, q = pq & 3;
    const int tid = threadIdx.x;
    const int c   = cam[b];

    float* xs  = stage;
    float* w1s = stage + 2048;

    const int ig = tid & 31;
    const int tg = tid >> 5;

    float acc[8][4];
    #pragma unroll
    for (int a = 0; a < 8; ++a)
        #pragma unroll
        for (int j = 0; j < 4; ++j) acc[a][j] = 0.f;

    for (int f0 = 0; f0 < F_; f0 += 32) {
        __syncthreads();
        {
            int lane = tid & 63;
            int sub  = tid >> 6;
            if (lane < T_) {
                #pragma unroll
                for (int m = 0; m < 8; ++m) {
                    int kk = sub * 8 + m;
                    xs[kk * 64 + lane] = x[((size_t)b * F_ + f0 + kk) * T_ + lane];
                }
            }
        }
        for (int e = tid; e < 32 * H1_; e += 256) {
            int kk = e >> 7, i = e & 127;
            w1s[e] = W1[(((size_t)c * F_ + f0 + kk) * H1_ + i) * 12 + pq];
        }
        __syncthreads();
        #pragma unroll 8
        for (int kk = 0; kk < 32; ++kk) {
            float4 bv = *(const float4*)&w1s[kk * 128 + ig * 4];
            float4 a0 = *(const float4*)&xs[kk * 64 + tg * 8];
            float4 a1 = *(const float4*)&xs[kk * 64 + tg * 8 + 4];
            float at[8] = {a0.x, a0.y, a0.z, a0.w, a1.x, a1.y, a1.z, a1.w};
            #pragma unroll
            for (int tt = 0; tt < 8; ++tt) {
                acc[tt][0] = fmaf(at[tt], bv.x, acc[tt][0]);
                acc[tt][1] = fmaf(at[tt], bv.y, acc[tt][1]);
                acc[tt][2] = fmaf(at[tt], bv.z, acc[tt][2]);
                acc[tt][3] = fmaf(at[tt], bv.w, acc[tt][3]);
            }
        }
    }
    {
        float4 b1v = *(const float4*)&b1[c * H1_ + ig * 4];
        #pragma unroll
        for (int tt = 0; tt < 8; ++tt) {
            int t = tg * 8 + tt;
            if (t < T_) {
                float4 hv;
                hv.x = fmaxf(acc[tt][0] + b1v.x, 0.f);
                hv.y = fmaxf(acc[tt][1] + b1v.y, 0.f);
                hv.z = fmaxf(acc[tt][2] + b1v.z, 0.f);
                hv.w = fmaxf(acc[tt][3] + b1v.w, 0.f);
                *(float4*)&h1s[t * H1_ + ig * 4] = hv;
            }
        }
    }

    const int lane = tid & 63;
    const int wv   = tid >> 6;
    const float w3v = W3[c * H2_ + lane];
    const float b2v = b2[c * H2_ + lane];
    const float b3v = b3[c];
    float* w2s = stage;

    for (int rs = 0; rs < 12; ++rs) {
        __syncthreads();
        for (int e = tid; e < H1_ * H2_; e += 256) {
            int i = e >> 6, o = e & 63;
            w2s[e] = W2[(((size_t)c * H1_ + i) * H2_ + o) * 12 + rs];
        }
        __syncthreads();

        float acc2[15];
        #pragma unroll
        for (int j = 0; j < 15; ++j) acc2[j] = 0.f;

        for (int i = 0; i < H1_; i += 4) {
            float wa = w2s[(i + 0) * 64 + lane];
            float wb = w2s[(i + 1) * 64 + lane];
            float wc = w2s[(i + 2) * 64 + lane];
            float wd = w2s[(i + 3) * 64 + lane];
            #pragma unroll
            for (int j = 0; j < 15; ++j) {
                float4 h = *(const float4*)&h1s[(wv * 15 + j) * H1_ + i];
                acc2[j] = fmaf(h.x, wa, acc2[j]);
                acc2[j] = fmaf(h.y, wb, acc2[j]);
                acc2[j] = fmaf(h.z, wc, acc2[j]);
                acc2[j] = fmaf(h.w, wd, acc2[j]);
            }
        }

        const int r = rs >> 2, s = rs & 3;
        const int hrow = p * 3 + r, wcol = q * 4 + s;
        #pragma unroll
        for (int j = 0; j < 15; ++j) {
            float y = w3v * fmaxf(acc2[j] + b2v, 0.f);
            #pragma unroll
            for (int m = 32; m > 0; m >>= 1) y += __shfl_xor(y, m, 64);
            if (lane == j) {
                int t = wv * 15 + j;
                float v = y + b3v;
                out[(((size_t)b * T_ + t) * 9 + hrow) * 16 + wcol] = 1.f / (1.f + __expf(-v));
            }
        }
    }
}

// ---------------------------------------------------------------------------
extern "C" void kernel_launch(void* const* d_in, const int* in_sizes, int n_in,
                              void* d_out, int out_size, void* d_ws, size_t ws_size,
                              hipStream_t stream) {
    const float* x   = (const float*)d_in[0];
    const int*   cam = (const int*)  d_in[1];
    const float* W1  = (const float*)d_in[2];
    const float* b1  = (const float*)d_in[3];
    const float* W2  = (const float*)d_in[4];
    const float* b2  = (const float*)d_in[5];
    const float* W3  = (const float*)d_in[6];
    const float* b3  = (const float*)d_in[7];
    float* outp = (float*)d_out;

    const size_t n_xT  = (size_t)B_ * 64 * F_;          //  4,194,304
    const size_t n_w1b = (size_t)C_ * 12 * H1_ * F_;    // 11,796,480
    const size_t n_w2b = (size_t)C_ * 12 * H2_ * H1_;   //  1,474,560
    const size_t needed = (n_xT + n_w1b + n_w2b) * sizeof(unsigned short);

    if (d_ws != nullptr && ws_size >= needed) {
        unsigned short* xT  = (unsigned short*)d_ws;
        unsigned short* W1p = xT + n_xT;
        unsigned short* W2p = W1p + n_w1b;
        repack_x <<<dim3(4, B_), 256, 0, stream>>>(x, xT);
        repack_w1<<<dim3(F_ / 32, H1_ / 32, C_), 256, 0, stream>>>(W1, W1p);
        repack_w2<<<dim3(H1_ / 32, H2_ / 32, C_), 256, 0, stream>>>(W2, W2p);
        fused_mfma<<<dim3(12 * B_), 256, 0, stream>>>(
            xT, W1p, W2p, cam, b1, b2, W3, b3, outp);
    } else {
        fused_decoder_f32<<<dim3(12, B_), 256, 0, stream>>>(
            x, cam, W1, b1, W2, b2, W3, b3, outp);
    }
}